// Round 5
// baseline (84.887 us; speedup 1.0000x reference)
//
#include <hip/hip_runtime.h>

// IMU preintegration, B=32 batches, F=8192 steps. Chunk-parallel pipeline:
//  A k_chunktot : wave=64-step chunk -> chunk quat totals      (scratch in outv)
//  B k_qpre     : per-batch exclusive scan of 128 chunk quats  (scratch in outv)
//  C k_main     : outq + vel/pos chunk partials + cov composites
//                 (S-term reduce via per-wave LDS transpose, 45 unique elems)
//  D k_vpscan   : per-batch scans of vel/pos chunk partials -> (V,Pp) per chunk
//  E k_emit     : final vel/pos
//  K4 k_covcomb : combine 128 cov composites -> 9x9 per batch
// d_ws: cov composites 32*128*73 fl + vpre 32*128*8 fl = 1,327,104 bytes.

#define BB 32
#define FF 8192
#define NCH 128
#define SLOT 73
#define GRAV 9.81007f
#define GCOV (0.0032f*0.0032f)
#define ACOV (0.08f*0.08f)

// ws float offsets
#define COV_OFF  0              // 32*128*73 = 299008 floats
#define VPRE_OFF 299008         // 32768 floats
// scratch offsets inside outv region (floats)
#define QTOT_SOFF 0
#define QPRE_SOFF 16384
#define VP_SOFF   32768

struct Quat { float x, y, z, w; };

__device__ __forceinline__ Quat qmul(const Quat a, const Quat b) {
    Quat r;
    r.x = a.w*b.x + a.x*b.w + a.y*b.z - a.z*b.y;
    r.y = a.w*b.y - a.x*b.z + a.y*b.w + a.z*b.x;
    r.z = a.w*b.z + a.x*b.y - a.y*b.x + a.z*b.w;
    r.w = a.w*b.w - a.x*b.x - a.y*b.y - a.z*b.z;
    return r;
}

__device__ __forceinline__ Quat qshfl_up(const Quat a, int s) {
    Quat r;
    r.x=__shfl_up(a.x,s); r.y=__shfl_up(a.y,s);
    r.z=__shfl_up(a.z,s); r.w=__shfl_up(a.w,s);
    return r;
}

__device__ __forceinline__ Quat qexp3(float px, float py, float pz) {
    float th2 = px*px + py*py + pz*pz;
    float s, w;
    if (th2 < 1e-8f) {
        s = 0.5f - th2 * (1.0f/48.0f);
        w = 1.0f - th2 * 0.125f;
    } else {
        float th = sqrtf(th2);
        s = sinf(0.5f*th) / th;
        w = cosf(0.5f*th);
    }
    Quat q; q.x=px*s; q.y=py*s; q.z=pz*s; q.w=w; return q;
}

__device__ __forceinline__ void quat2mat(const Quat q, float* R) {
    float x=q.x, y=q.y, z=q.z, w=q.w;
    R[0]=1.0f-2.0f*(y*y+z*z); R[1]=2.0f*(x*y-z*w);       R[2]=2.0f*(x*z+y*w);
    R[3]=2.0f*(x*y+z*w);      R[4]=1.0f-2.0f*(x*x+z*z);  R[5]=2.0f*(y*z-x*w);
    R[6]=2.0f*(x*z-y*w);      R[7]=2.0f*(y*z+x*w);       R[8]=1.0f-2.0f*(x*x+y*y);
}

__device__ __forceinline__ void mm_nn(const float* A, const float* B, float* C) {
#pragma unroll
    for (int i=0;i<3;i++)
#pragma unroll
    for (int j=0;j<3;j++)
        C[3*i+j] = A[3*i+0]*B[0+j] + A[3*i+1]*B[3+j] + A[3*i+2]*B[6+j];
}

__device__ __forceinline__ void mm_nt(const float* A, const float* B, float* C) {
#pragma unroll
    for (int i=0;i<3;i++)
#pragma unroll
    for (int j=0;j<3;j++)
        C[3*i+j] = A[3*i+0]*B[3*j+0] + A[3*i+1]*B[3*j+1] + A[3*i+2]*B[3*j+2];
}

// upper triangle of A*B^T when the product is symmetric: (0,0)(0,1)(0,2)(1,1)(1,2)(2,2)
__device__ __forceinline__ void mm_nt_sym(const float* A, const float* B, float* O6) {
    O6[0]=A[0]*B[0]+A[1]*B[1]+A[2]*B[2];
    O6[1]=A[0]*B[3]+A[1]*B[4]+A[2]*B[5];
    O6[2]=A[0]*B[6]+A[1]*B[7]+A[2]*B[8];
    O6[3]=A[3]*B[3]+A[4]*B[4]+A[5]*B[5];
    O6[4]=A[3]*B[6]+A[4]*B[7]+A[5]*B[8];
    O6[5]=A[6]*B[6]+A[7]*B[7]+A[8]*B[8];
}

// ---------------------------------------------------------------------------
// A: chunk quaternion totals. wave = one 64-step chunk.
// ---------------------------------------------------------------------------
__global__ __launch_bounds__(256) void k_chunktot(
    const float* __restrict__ dt, const float* __restrict__ gyro,
    float* __restrict__ scr)
{
    const int bid=blockIdx.x, b=bid>>5, wg=bid&31;
    const int tid=threadIdx.x, lane=tid&63, wid=tid>>6;
    const int c=wg*4+wid;
    const long k=(long)b*FF+(long)c*64+lane;
    float d=dt[k];
    Quat inc=qexp3(gyro[3*k+0]*d, gyro[3*k+1]*d, gyro[3*k+2]*d);
#pragma unroll
    for (int s=1;s<64;s<<=1) {
        Quat p=qshfl_up(inc,s);
        if (lane>=s) inc=qmul(p,inc);
    }
    if (lane==63) {
        float4 o; o.x=inc.x; o.y=inc.y; o.z=inc.z; o.w=inc.w;
        reinterpret_cast<float4*>(scr+QTOT_SOFF)[b*NCH+c]=o;
    }
}

// ---------------------------------------------------------------------------
// B: exclusive scan of 128 chunk quats per batch. 1 WG/batch, 128 threads.
// ---------------------------------------------------------------------------
__global__ __launch_bounds__(128) void k_qpre(float* __restrict__ scr)
{
    const int b=blockIdx.x, c=threadIdx.x, lane=c&63, w=c>>6;
    __shared__ float4 w0t;
    __shared__ float4 all[NCH];
    float4 t=reinterpret_cast<const float4*>(scr+QTOT_SOFF)[b*NCH+c];
    Quat inc; inc.x=t.x; inc.y=t.y; inc.z=t.z; inc.w=t.w;
#pragma unroll
    for (int s=1;s<64;s<<=1) {
        Quat p=qshfl_up(inc,s);
        if (lane>=s) inc=qmul(p,inc);
    }
    if (w==0 && lane==63) { float4 o; o.x=inc.x;o.y=inc.y;o.z=inc.z;o.w=inc.w; w0t=o; }
    __syncthreads();
    if (w==1) { Quat p; p.x=w0t.x;p.y=w0t.y;p.z=w0t.z;p.w=w0t.w; inc=qmul(p,inc); }
    { float4 o; o.x=inc.x;o.y=inc.y;o.z=inc.z;o.w=inc.w; all[c]=o; }
    __syncthreads();
    float4 pre;
    if (c==0) { pre.x=0.f;pre.y=0.f;pre.z=0.f;pre.w=1.f; }
    else pre=all[c-1];
    reinterpret_cast<float4*>(scr+QPRE_SOFF)[b*NCH+c]=pre;
}

// ---------------------------------------------------------------------------
// C: main fused kernel. wave = chunk. Writes outq, vel/pos chunk partials,
//    covariance chunk composites (Phi 28 + S 45 unique floats per chunk).
// ---------------------------------------------------------------------------
#define RSTR 66
__global__ __launch_bounds__(256) void k_main(
    const float* __restrict__ dt, const float* __restrict__ gyro,
    const float* __restrict__ acc, float* __restrict__ scr,
    float* __restrict__ outq, float* __restrict__ cov)
{
    __shared__ float red[4][23][RSTR];   // 24,288 B
    const int bid=blockIdx.x, b=bid>>5, wg=bid&31;
    const int tid=threadIdx.x, lane=tid&63, wid=tid>>6;
    const int c=wg*4+wid;
    const long k=(long)b*FF+(long)c*64+lane;

    const float d=dt[k];
    const float wx=gyro[3*k+0]*d, wy=gyro[3*k+1]*d, wz=gyro[3*k+2]*d;
    Quat dq=qexp3(wx,wy,wz);

    // within-chunk inclusive quat prefix
    Quat qloc=dq;
#pragma unroll
    for (int s=1;s<64;s<<=1) {
        Quat p=qshfl_up(qloc,s);
        if (lane>=s) qloc=qmul(p,qloc);
    }
    float4 tp=reinterpret_cast<const float4*>(scr+QPRE_SOFF)[b*NCH+c];
    Quat qpre; qpre.x=tp.x; qpre.y=tp.y; qpre.z=tp.z; qpre.w=tp.w;
    Quat qi=qmul(qpre,qloc);
    { float4 o; o.x=qi.x;o.y=qi.y;o.z=qi.z;o.w=qi.w;
      reinterpret_cast<float4*>(outq)[k]=o; }

    Quat ql1=qshfl_up(qloc,1);
    Quat qp = (lane==0) ? qpre : qmul(qpre,ql1);

    // a = acc - R(qi)^T g
    float a0=acc[3*k+0]-GRAV*2.0f*(qi.x*qi.z-qi.y*qi.w);
    float a1=acc[3*k+1]-GRAV*2.0f*(qi.y*qi.z+qi.x*qi.w);
    float a2=acc[3*k+2]-GRAV*(1.0f-2.0f*(qi.x*qi.x+qi.y*qi.y));

    float Rp[9]; quat2mat(qp,Rp);
    float s0=(Rp[0]*a0+Rp[1]*a1+Rp[2]*a2)*d;
    float s1=(Rp[3]*a0+Rp[4]*a1+Rp[5]*a2)*d;
    float s2=(Rp[6]*a0+Rp[7]*a1+Rp[8]*a2)*d;

    // chunk vel/pos partials
    float td=d, l0=s0, l1=s1, l2=s2;
#pragma unroll
    for (int s=1;s<64;s<<=1) {
        float p3=__shfl_up(td,s), p0=__shfl_up(l0,s), p1=__shfl_up(l1,s), p2=__shfl_up(l2,s);
        if (lane>=s) { td+=p3; l0+=p0; l1+=p1; l2+=p2; }
    }
    float w0=(l0-s0)*d+0.5f*s0*d;
    float w1=(l1-s1)*d+0.5f*s1*d;
    float w2=(l2-s2)*d+0.5f*s2*d;
#pragma unroll
    for (int m=1;m<64;m<<=1) {
        w0+=__shfl_xor(w0,m); w1+=__shfl_xor(w1,m); w2+=__shfl_xor(w2,m);
    }
    if (lane==63) {
        float* vp=scr+VP_SOFF+(long)(b*NCH+c)*8;
        vp[0]=l0; vp[1]=l1; vp[2]=l2; vp[3]=w0; vp[4]=w1; vp[5]=w2; vp[6]=td;
    }

    // ---- covariance composite ----
    float Rd[9]; quat2mat(dq,Rd);
    float D[9];
    D[0]=Rd[0]; D[1]=Rd[3]; D[2]=Rd[6];
    D[3]=Rd[1]; D[4]=Rd[4]; D[5]=Rd[7];
    D[6]=Rd[2]; D[7]=Rd[5]; D[8]=Rd[8];

    float P[9], Q[9];
#pragma unroll
    for (int i=0;i<3;i++) {
        float r0=Rp[3*i+0], r1=Rp[3*i+1], r2=Rp[3*i+2];
        float Ra0 = a2*r1 - a1*r2;
        float Ra1 = a0*r2 - a2*r0;
        float Ra2 = a1*r0 - a0*r1;
        P[3*i+0] = -d*Ra0; P[3*i+1] = -d*Ra1; P[3*i+2] = -d*Ra2;
        Q[3*i+0] = 0.5f*d*P[3*i+0]; Q[3*i+1] = 0.5f*d*P[3*i+1]; Q[3*i+2] = 0.5f*d*P[3*i+2];
    }
    float T = d;

    float th2 = wx*wx + wy*wy + wz*wz;
    float c1, c2;
    if (th2 < 1e-8f) { c1 = 0.5f - th2*(1.0f/24.0f); c2 = (1.0f/6.0f) - th2*(1.0f/120.0f); }
    else { float th = sqrtf(th2); c1 = (1.0f-cosf(th))/th2; c2 = (th - sinf(th))/(th2*th); }
    float J[9];
    {
        float dg = 1.0f - c2*th2;
        J[0]=dg + c2*wx*wx;      J[1]= c1*wz + c2*wx*wy;  J[2]=-c1*wy + c2*wx*wz;
        J[3]=-c1*wz + c2*wx*wy;  J[4]=dg + c2*wy*wy;      J[5]= c1*wx + c2*wy*wz;
        J[6]= c1*wy + c2*wx*wz;  J[7]=-c1*wx + c2*wy*wz;  J[8]=dg + c2*wz*wz;
    }
    float G[9]; mm_nt(J, J, G);
    {
        float gs = GCOV*d*d;
#pragma unroll
        for (int i=0;i<9;i++) G[i] *= gs;
    }
    const float av = ACOV*d*d;
    const float bv = 0.5f*ACOV*d*d*d;
    const float cv = 0.25f*ACOV*d*d*d*d;

    // wave inclusive suffix scan of (D,P,Q,T)
#pragma unroll
    for (int s=1;s<64;s<<=1) {
        float pD[9], pP[9], pQ[9], pT;
#pragma unroll
        for (int i=0;i<9;i++){ pD[i]=__shfl_down(D[i],s); pP[i]=__shfl_down(P[i],s); pQ[i]=__shfl_down(Q[i],s); }
        pT = __shfl_down(T, s);
        if (lane + s < 64) {
            float nD[9], nP[9], nQ[9];
            mm_nn(pD, D, nD); mm_nn(pP, D, nP); mm_nn(pQ, D, nQ);
#pragma unroll
            for (int i=0;i<9;i++){
                float np = nP[i] + P[i];
                float nq = nQ[i] + pT*P[i] + Q[i];
                D[i]=nD[i]; P[i]=np; Q[i]=nq;
            }
            T += pT;
        }
    }
    const long wsbase = ((long)b*NCH + c)*SLOT;
    if (lane==0) {
#pragma unroll
        for (int i=0;i<9;i++){ cov[wsbase+i]=D[i]; cov[wsbase+9+i]=P[i]; cov[wsbase+18+i]=Q[i]; }
        cov[wsbase+27] = T;
    }
    // exclusive suffix shift
    {
        float pD[9], pP[9], pQ[9], pT;
#pragma unroll
        for (int i=0;i<9;i++){ pD[i]=__shfl_down(D[i],1); pP[i]=__shfl_down(P[i],1); pQ[i]=__shfl_down(Q[i],1); }
        pT = __shfl_down(T, 1);
        if (lane==63) {
#pragma unroll
            for (int i=0;i<9;i++){ D[i]=(i%4==0)?1.f:0.f; P[i]=0.f; Q[i]=0.f; }
            T = 0.f;
        } else {
#pragma unroll
            for (int i=0;i<9;i++){ D[i]=pD[i]; P[i]=pP[i]; Q[i]=pQ[i]; }
            T = pT;
        }
    }
    // term = Psi N Psi^T, 45 unique elements:
    //  0-8 Arv | 9-17 Arp | 18-26 Avp | 27-32 Arr(sym) | 33-38 Avv(sym) | 39-44 App(sym)
    float S45[45];
    {
        float M1[9];
        mm_nn(D, G, M1);
        mm_nt_sym(M1, D, S45+27);       // Arr
        mm_nt(M1, P, S45+0);            // Arv
        mm_nt(M1, Q, S45+9);            // Arp
        mm_nn(P, G, M1);
        mm_nt_sym(M1, P, S45+33);       // Avv
        mm_nt(M1, Q, S45+18);           // Avp
        mm_nn(Q, G, M1);
        mm_nt_sym(M1, Q, S45+39);       // App
        S45[33]+=av; S45[36]+=av; S45[38]+=av;
        float vpd = av*T + bv;
        S45[18]+=vpd; S45[22]+=vpd; S45[26]+=vpd;
        float ppd = av*T*T + 2.0f*bv*T + cv;
        S45[39]+=ppd; S45[42]+=ppd; S45[44]+=ppd;
    }

    // per-wave LDS transpose reduction over lanes, two rounds (23 + 22 elems)
#pragma unroll
    for (int e=0;e<23;e++) red[wid][e][lane] = S45[e];
    __syncthreads();
    float r1 = 0.f;
    if (lane < 23) {
        const float* row = &red[wid][lane][0];
        float ax=0.f, ay=0.f;
#pragma unroll
        for (int i=0;i<32;i++) {
            float2 v = reinterpret_cast<const float2*>(row)[i];
            ax += v.x; ay += v.y;
        }
        r1 = ax + ay;
    }
    __syncthreads();
#pragma unroll
    for (int e=0;e<22;e++) red[wid][e][lane] = S45[23+e];
    __syncthreads();
    float r2 = 0.f;
    if (lane < 22) {
        const float* row = &red[wid][lane][0];
        float ax=0.f, ay=0.f;
#pragma unroll
        for (int i=0;i<32;i++) {
            float2 v = reinterpret_cast<const float2*>(row)[i];
            ax += v.x; ay += v.y;
        }
        r2 = ax + ay;
    }
    if (lane < 23) cov[wsbase+28+lane] = r1;
    if (lane < 22) cov[wsbase+28+23+lane] = r2;
}

// ---------------------------------------------------------------------------
// D: per-batch scans of vel/pos chunk partials -> exclusive (V, Pp) per chunk.
// ---------------------------------------------------------------------------
__global__ __launch_bounds__(128) void k_vpscan(
    const float* __restrict__ scr, float* __restrict__ vpre)
{
    const int b=blockIdx.x, c=threadIdx.x, lane=c&63, w=c>>6;
    __shared__ float w0t[3];
    __shared__ float all3[NCH][3];
    const float* vp=scr+VP_SOFF+(long)(b*NCH+c)*8;
    float Lv0=vp[0],Lv1=vp[1],Lv2=vp[2],Sw0=vp[3],Sw1=vp[4],Sw2=vp[5],Td=vp[6];

    float i0=Lv0,i1=Lv1,i2=Lv2;
#pragma unroll
    for (int s=1;s<64;s<<=1) {
        float p0=__shfl_up(i0,s),p1=__shfl_up(i1,s),p2=__shfl_up(i2,s);
        if (lane>=s){ i0+=p0; i1+=p1; i2+=p2; }
    }
    if (w==0 && lane==63){ w0t[0]=i0; w0t[1]=i1; w0t[2]=i2; }
    __syncthreads();
    if (w==1){ i0+=w0t[0]; i1+=w0t[1]; i2+=w0t[2]; }
    all3[c][0]=i0; all3[c][1]=i1; all3[c][2]=i2;
    __syncthreads();
    float V0=(c==0)?0.f:all3[c-1][0];
    float V1=(c==0)?0.f:all3[c-1][1];
    float V2=(c==0)?0.f:all3[c-1][2];
    __syncthreads();

    float u0=V0*Td+Sw0, u1=V1*Td+Sw1, u2=V2*Td+Sw2;
    i0=u0; i1=u1; i2=u2;
#pragma unroll
    for (int s=1;s<64;s<<=1) {
        float p0=__shfl_up(i0,s),p1=__shfl_up(i1,s),p2=__shfl_up(i2,s);
        if (lane>=s){ i0+=p0; i1+=p1; i2+=p2; }
    }
    if (w==0 && lane==63){ w0t[0]=i0; w0t[1]=i1; w0t[2]=i2; }
    __syncthreads();
    if (w==1){ i0+=w0t[0]; i1+=w0t[1]; i2+=w0t[2]; }
    all3[c][0]=i0; all3[c][1]=i1; all3[c][2]=i2;
    __syncthreads();
    float P0=(c==0)?0.f:all3[c-1][0];
    float P1=(c==0)?0.f:all3[c-1][1];
    float P2=(c==0)?0.f:all3[c-1][2];

    float* o=vpre+(long)(b*NCH+c)*8;
    o[0]=V0; o[1]=V1; o[2]=V2; o[3]=P0; o[4]=P1; o[5]=P2;
}

// ---------------------------------------------------------------------------
// E: final vel/pos emit. wave = chunk.
// ---------------------------------------------------------------------------
__global__ __launch_bounds__(256) void k_emit(
    const float* __restrict__ dt, const float* __restrict__ acc,
    const float* __restrict__ q, const float* __restrict__ pos0,
    const float* __restrict__ vel0, const float* __restrict__ vpre,
    float* __restrict__ outv, float* __restrict__ outp)
{
    const int bid=blockIdx.x, b=bid>>5, wg=bid&31;
    const int tid=threadIdx.x, lane=tid&63, wid=tid>>6;
    const int c=wg*4+wid;
    const long k=(long)b*FF+(long)c*64+lane;

    const float d=dt[k];
    float4 tq=reinterpret_cast<const float4*>(q)[k];
    Quat qi; qi.x=tq.x; qi.y=tq.y; qi.z=tq.z; qi.w=tq.w;

    float a0=acc[3*k+0]-GRAV*2.0f*(qi.x*qi.z-qi.y*qi.w);
    float a1=acc[3*k+1]-GRAV*2.0f*(qi.y*qi.z+qi.x*qi.w);
    float a2=acc[3*k+2]-GRAV*(1.0f-2.0f*(qi.x*qi.x+qi.y*qi.y));

    Quat qp=qshfl_up(qi,1);
    if (lane==0) {
        if (c==0) { qp.x=0.f; qp.y=0.f; qp.z=0.f; qp.w=1.f; }
        else { float4 t2=reinterpret_cast<const float4*>(q)[k-1];
               qp.x=t2.x; qp.y=t2.y; qp.z=t2.z; qp.w=t2.w; }
    }
    float Rp[9]; quat2mat(qp,Rp);
    float s0=(Rp[0]*a0+Rp[1]*a1+Rp[2]*a2)*d;
    float s1=(Rp[3]*a0+Rp[4]*a1+Rp[5]*a2)*d;
    float s2=(Rp[6]*a0+Rp[7]*a1+Rp[8]*a2)*d;

    float td=d, l0=s0, l1=s1, l2=s2;
#pragma unroll
    for (int s=1;s<64;s<<=1) {
        float p3=__shfl_up(td,s), p0=__shfl_up(l0,s), p1=__shfl_up(l1,s), p2=__shfl_up(l2,s);
        if (lane>=s) { td+=p3; l0+=p0; l1+=p1; l2+=p2; }
    }
    float w0=(l0-s0)*d+0.5f*s0*d;
    float w1=(l1-s1)*d+0.5f*s1*d;
    float w2=(l2-s2)*d+0.5f*s2*d;
    float sw0=w0, sw1=w1, sw2=w2;
#pragma unroll
    for (int s=1;s<64;s<<=1) {
        float p0=__shfl_up(sw0,s),p1=__shfl_up(sw1,s),p2=__shfl_up(sw2,s);
        if (lane>=s){ sw0+=p0; sw1+=p1; sw2+=p2; }
    }

    const float* vr=vpre+(long)(b*NCH+c)*8;
    float V0=vr[0],V1=vr[1],V2=vr[2],P0=vr[3],P1=vr[4],P2=vr[5];
    float v0x=vel0[3*b+0], v0y=vel0[3*b+1], v0z=vel0[3*b+2];
    float p0x=pos0[3*b+0], p0y=pos0[3*b+1], p0z=pos0[3*b+2];

    outv[3*k+0]=v0x+V0+l0;
    outv[3*k+1]=v0y+V1+l1;
    outv[3*k+2]=v0z+V2+l2;
    outp[3*k+0]=p0x+P0+V0*td+sw0;
    outp[3*k+1]=p0y+P1+V1*td+sw1;
    outp[3*k+2]=p0z+P2+V2*td+sw2;
}

// ---------------------------------------------------------------------------
// K4: combine 128 chunk composites per batch -> final 9x9 covariance.
// ---------------------------------------------------------------------------
__device__ __forceinline__ void congr(const float* D, const float* P, const float* Q, float T,
                                      const float* S, float* O)
{
    const float* Arr=S+0;  const float* Arv=S+9;  const float* Arp=S+18;
    const float* Avv=S+27; const float* Avp=S+36; const float* App=S+45;
    float M1[9], M2[9], M3[9], t1[9];
    mm_nn(D, Arr, M1); mm_nn(D, Arv, M2); mm_nn(D, Arp, M3);
    mm_nt(M1, D, O+0);
    mm_nt(M1, P, t1);
#pragma unroll
    for (int i=0;i<9;i++) O[9+i] = t1[i] + M2[i];
    mm_nt(M1, Q, t1);
#pragma unroll
    for (int i=0;i<9;i++) O[18+i] = t1[i] + T*M2[i] + M3[i];
    float W1[9], W2[9], W3[9];
    mm_nn(P, Arr, W1);
#pragma unroll
    for (int i=0;i<3;i++)
#pragma unroll
    for (int j=0;j<3;j++) W1[3*i+j] += Arv[3*j+i];
    mm_nn(P, Arv, W2);
#pragma unroll
    for (int i=0;i<9;i++) W2[i] += Avv[i];
    mm_nn(P, Arp, W3);
#pragma unroll
    for (int i=0;i<9;i++) W3[i] += Avp[i];
    mm_nt(W1, P, t1);
#pragma unroll
    for (int i=0;i<9;i++) O[27+i] = t1[i] + W2[i];
    mm_nt(W1, Q, t1);
#pragma unroll
    for (int i=0;i<9;i++) O[36+i] = t1[i] + T*W2[i] + W3[i];
    float U1[9], U2[9], U3[9];
    mm_nn(Q, Arr, U1);
#pragma unroll
    for (int i=0;i<3;i++)
#pragma unroll
    for (int j=0;j<3;j++) U1[3*i+j] += T*Arv[3*j+i] + Arp[3*j+i];
    mm_nn(Q, Arv, U2);
#pragma unroll
    for (int i=0;i<3;i++)
#pragma unroll
    for (int j=0;j<3;j++) U2[3*i+j] += T*Avv[3*i+j] + Avp[3*j+i];
    mm_nn(Q, Arp, U3);
#pragma unroll
    for (int i=0;i<9;i++) U3[i] += T*Avp[i] + App[i];
    mm_nt(U1, Q, t1);
#pragma unroll
    for (int i=0;i<9;i++) O[45+i] = t1[i] + T*U2[i] + U3[i];
}

__global__ __launch_bounds__(128) void k_covcomb(
    const float* __restrict__ cov, float* __restrict__ outc)
{
    __shared__ float cp[NCH*82];
    const int b = blockIdx.x;
    const int c = threadIdx.x;
    // load 73-float slots, expand symmetric blocks into 82-float cp layout
    for (int idx=c; idx<NCH*SLOT; idx+=128) {
        int ch = idx/SLOT, f = idx%SLOT;
        float v = cov[(long)b*NCH*SLOT + idx];
        if (f < 28) cp[ch*82+f] = v;
        else {
            int s = f-28;
            if (s < 9)       cp[ch*82+28+9+s]      = v;  // Arv
            else if (s < 18) cp[ch*82+28+18+(s-9)] = v;  // Arp
            else if (s < 27) cp[ch*82+28+36+(s-18)]= v;  // Avp
            else {
                int m, blk;
                if (s < 33)      { m = s-27; blk = 0;  } // Arr
                else if (s < 39) { m = s-33; blk = 27; } // Avv
                else             { m = s-39; blk = 45; } // App
                int r  = (m<3)?0:((m<5)?1:2);
                int cc = (m<3)?m:((m<5)?m-2:2);
                cp[ch*82+28+blk+3*r+cc] = v;
                cp[ch*82+28+blk+3*cc+r] = v;
            }
        }
    }
    __syncthreads();

    for (int s=1;s<NCH;s<<=1) {
        float aD[9],aP[9],aQ[9],aT=0.f;
        float bD[9],bP[9],bQ[9],bT;
        bool act = (c+s) < NCH;
#pragma unroll
        for (int i=0;i<9;i++){ bD[i]=cp[c*82+i]; bP[i]=cp[c*82+9+i]; bQ[i]=cp[c*82+18+i]; }
        bT = cp[c*82+27];
        if (act) {
#pragma unroll
            for (int i=0;i<9;i++){ aD[i]=cp[(c+s)*82+i]; aP[i]=cp[(c+s)*82+9+i]; aQ[i]=cp[(c+s)*82+18+i]; }
            aT = cp[(c+s)*82+27];
        }
        __syncthreads();
        if (act) {
            float nD[9], nP[9], nQ[9];
            mm_nn(aD, bD, nD); mm_nn(aP, bD, nP); mm_nn(aQ, bD, nQ);
#pragma unroll
            for (int i=0;i<9;i++){
                cp[c*82+i]    = nD[i];
                cp[c*82+9+i]  = nP[i] + bP[i];
                cp[c*82+18+i] = nQ[i] + aT*bP[i] + bQ[i];
            }
            cp[c*82+27] = aT + bT;
        }
        __syncthreads();
    }

    float D[9], P[9], Q[9], T;
    if (c < NCH-1) {
#pragma unroll
        for (int i=0;i<9;i++){ D[i]=cp[(c+1)*82+i]; P[i]=cp[(c+1)*82+9+i]; Q[i]=cp[(c+1)*82+18+i]; }
        T = cp[(c+1)*82+27];
    } else {
#pragma unroll
        for (int i=0;i<9;i++){ D[i]=(i%4==0)?1.f:0.f; P[i]=0.f; Q[i]=0.f; }
        T = 0.f;
    }
    float S[54], O[54];
#pragma unroll
    for (int i=0;i<54;i++) S[i] = cp[c*82+28+i];
    congr(D, P, Q, T, S, O);
#pragma unroll
    for (int i=0;i<54;i++) cp[c*82+28+i] = O[i];
    __syncthreads();

    for (int s=64;s>0;s>>=1) {
        if (c < s) {
#pragma unroll
            for (int i=0;i<54;i++) cp[c*82+28+i] += cp[(c+s)*82+28+i];
        }
        __syncthreads();
    }

    if (c < 81) {
        int i = c/9, j = c%9;
        int bi = i/3, ii = i%3, bj = j/3, jj = j%3;
        const float* S0 = &cp[28];
        float v;
        if      (bi==0 && bj==0) v = S0[0  + 3*ii + jj];
        else if (bi==0 && bj==1) v = S0[9  + 3*ii + jj];
        else if (bi==0 && bj==2) v = S0[18 + 3*ii + jj];
        else if (bi==1 && bj==0) v = S0[9  + 3*jj + ii];
        else if (bi==1 && bj==1) v = S0[27 + 3*ii + jj];
        else if (bi==1 && bj==2) v = S0[36 + 3*ii + jj];
        else if (bi==2 && bj==0) v = S0[18 + 3*jj + ii];
        else if (bi==2 && bj==1) v = S0[36 + 3*jj + ii];
        else                     v = S0[45 + 3*ii + jj];
        outc[(long)b*81 + c] = v;
    }
}

// ---------------------------------------------------------------------------
extern "C" void kernel_launch(void* const* d_in, const int* in_sizes, int n_in,
                              void* d_out, int out_size, void* d_ws, size_t ws_size,
                              hipStream_t stream)
{
    const float* dt   = (const float*)d_in[0];
    const float* gyro = (const float*)d_in[1];
    const float* acc  = (const float*)d_in[2];
    const float* pos0 = (const float*)d_in[3];
    const float* vel0 = (const float*)d_in[4];

    float* out  = (float*)d_out;
    float* outq = out;
    float* outv = out  + (long)BB*FF*4;
    float* outp = outv + (long)BB*FF*3;
    float* outc = outp + (long)BB*FF*3;

    float* ws   = (float*)d_ws;           // 1,327,104 bytes used
    float* cov  = ws + COV_OFF;
    float* vpre = ws + VPRE_OFF;
    float* scr  = outv;                   // staging scratch, consumed before E

    hipLaunchKernelGGL(k_chunktot, dim3(BB*32), dim3(256), 0, stream, dt, gyro, scr);
    hipLaunchKernelGGL(k_qpre,     dim3(BB),    dim3(128), 0, stream, scr);
    hipLaunchKernelGGL(k_main,     dim3(BB*32), dim3(256), 0, stream, dt, gyro, acc, scr, outq, cov);
    hipLaunchKernelGGL(k_vpscan,   dim3(BB),    dim3(128), 0, stream, scr, vpre);
    hipLaunchKernelGGL(k_emit,     dim3(BB*32), dim3(256), 0, stream, dt, acc, outq, pos0, vel0, vpre, outv, outp);
    hipLaunchKernelGGL(k_covcomb,  dim3(BB),    dim3(128), 0, stream, cov, outc);
}

// Round 6
// 55.381 us; speedup vs baseline: 1.5328x; 1.5328x over previous
//
#include <hip/hip_runtime.h>

// IMU preintegration, B=32 batches, F=8192 steps. Chunk-parallel pipeline:
//  A k_chunktot : wave=64-step chunk -> chunk quat totals      (scratch in outv)
//  B k_qpre     : per-batch exclusive scan of 128 chunk quats  (scratch in outv)
//  C k_main     : outq + vel/pos chunk partials + cov composites
//                 (S-term reduce via per-wave LDS transpose, 45 unique elems)
//  D k_vpscan   : per-batch scans of vel/pos chunk partials -> (V,Pp) per chunk
//  E k_emit     : final vel/pos
//  K4 k_covcomb : combine 128 cov composites (compact 73-slot, triangle-aware)
// d_ws: cov composites 32*128*73 fl + vpre 32*128*8 fl = 1,327,104 bytes.

#define BB 32
#define FF 8192
#define NCH 128
#define SLOT 73
#define GRAV 9.81007f
#define GCOV (0.0032f*0.0032f)
#define ACOV (0.08f*0.08f)

// ws float offsets
#define COV_OFF  0              // 32*128*73 = 299008 floats
#define VPRE_OFF 299008         // 32768 floats
// scratch offsets inside outv region (floats)
#define QTOT_SOFF 0
#define QPRE_SOFF 16384
#define VP_SOFF   32768

struct Quat { float x, y, z, w; };

__device__ __forceinline__ Quat qmul(const Quat a, const Quat b) {
    Quat r;
    r.x = a.w*b.x + a.x*b.w + a.y*b.z - a.z*b.y;
    r.y = a.w*b.y - a.x*b.z + a.y*b.w + a.z*b.x;
    r.z = a.w*b.z + a.x*b.y - a.y*b.x + a.z*b.w;
    r.w = a.w*b.w - a.x*b.x - a.y*b.y - a.z*b.z;
    return r;
}

__device__ __forceinline__ Quat qshfl_up(const Quat a, int s) {
    Quat r;
    r.x=__shfl_up(a.x,s); r.y=__shfl_up(a.y,s);
    r.z=__shfl_up(a.z,s); r.w=__shfl_up(a.w,s);
    return r;
}

__device__ __forceinline__ Quat qexp3(float px, float py, float pz) {
    float th2 = px*px + py*py + pz*pz;
    float s, w;
    if (th2 < 1e-8f) {
        s = 0.5f - th2 * (1.0f/48.0f);
        w = 1.0f - th2 * 0.125f;
    } else {
        float th = sqrtf(th2);
        s = sinf(0.5f*th) / th;
        w = cosf(0.5f*th);
    }
    Quat q; q.x=px*s; q.y=py*s; q.z=pz*s; q.w=w; return q;
}

__device__ __forceinline__ void quat2mat(const Quat q, float* R) {
    float x=q.x, y=q.y, z=q.z, w=q.w;
    R[0]=1.0f-2.0f*(y*y+z*z); R[1]=2.0f*(x*y-z*w);       R[2]=2.0f*(x*z+y*w);
    R[3]=2.0f*(x*y+z*w);      R[4]=1.0f-2.0f*(x*x+z*z);  R[5]=2.0f*(y*z-x*w);
    R[6]=2.0f*(x*z-y*w);      R[7]=2.0f*(y*z+x*w);       R[8]=1.0f-2.0f*(x*x+y*y);
}

__device__ __forceinline__ void mm_nn(const float* A, const float* B, float* C) {
#pragma unroll
    for (int i=0;i<3;i++)
#pragma unroll
    for (int j=0;j<3;j++)
        C[3*i+j] = A[3*i+0]*B[0+j] + A[3*i+1]*B[3+j] + A[3*i+2]*B[6+j];
}

__device__ __forceinline__ void mm_nt(const float* A, const float* B, float* C) {
#pragma unroll
    for (int i=0;i<3;i++)
#pragma unroll
    for (int j=0;j<3;j++)
        C[3*i+j] = A[3*i+0]*B[3*j+0] + A[3*i+1]*B[3*j+1] + A[3*i+2]*B[3*j+2];
}

// entries (0,0)(0,1)(0,2)(1,1)(1,2)(2,2) of A*B^T
__device__ __forceinline__ void mm_nt_sym(const float* A, const float* B, float* O6) {
    O6[0]=A[0]*B[0]+A[1]*B[1]+A[2]*B[2];
    O6[1]=A[0]*B[3]+A[1]*B[4]+A[2]*B[5];
    O6[2]=A[0]*B[6]+A[1]*B[7]+A[2]*B[8];
    O6[3]=A[3]*B[3]+A[4]*B[4]+A[5]*B[5];
    O6[4]=A[3]*B[6]+A[4]*B[7]+A[5]*B[8];
    O6[5]=A[6]*B[6]+A[7]*B[7]+A[8]*B[8];
}

__device__ __forceinline__ void expand_sym(const float* t, float* M) {
    M[0]=t[0]; M[1]=t[1]; M[2]=t[2];
    M[3]=t[1]; M[4]=t[3]; M[5]=t[4];
    M[6]=t[2]; M[7]=t[4]; M[8]=t[5];
}

// ---------------------------------------------------------------------------
// A: chunk quaternion totals. wave = one 64-step chunk.
// ---------------------------------------------------------------------------
__global__ __launch_bounds__(256) void k_chunktot(
    const float* __restrict__ dt, const float* __restrict__ gyro,
    float* __restrict__ scr)
{
    const int bid=blockIdx.x, b=bid>>5, wg=bid&31;
    const int tid=threadIdx.x, lane=tid&63, wid=tid>>6;
    const int c=wg*4+wid;
    const long k=(long)b*FF+(long)c*64+lane;
    float d=dt[k];
    Quat inc=qexp3(gyro[3*k+0]*d, gyro[3*k+1]*d, gyro[3*k+2]*d);
#pragma unroll
    for (int s=1;s<64;s<<=1) {
        Quat p=qshfl_up(inc,s);
        if (lane>=s) inc=qmul(p,inc);
    }
    if (lane==63) {
        float4 o; o.x=inc.x; o.y=inc.y; o.z=inc.z; o.w=inc.w;
        reinterpret_cast<float4*>(scr+QTOT_SOFF)[b*NCH+c]=o;
    }
}

// ---------------------------------------------------------------------------
// B: exclusive scan of 128 chunk quats per batch. 1 WG/batch, 128 threads.
// ---------------------------------------------------------------------------
__global__ __launch_bounds__(128) void k_qpre(float* __restrict__ scr)
{
    const int b=blockIdx.x, c=threadIdx.x, lane=c&63, w=c>>6;
    __shared__ float4 w0t;
    __shared__ float4 all[NCH];
    float4 t=reinterpret_cast<const float4*>(scr+QTOT_SOFF)[b*NCH+c];
    Quat inc; inc.x=t.x; inc.y=t.y; inc.z=t.z; inc.w=t.w;
#pragma unroll
    for (int s=1;s<64;s<<=1) {
        Quat p=qshfl_up(inc,s);
        if (lane>=s) inc=qmul(p,inc);
    }
    if (w==0 && lane==63) { float4 o; o.x=inc.x;o.y=inc.y;o.z=inc.z;o.w=inc.w; w0t=o; }
    __syncthreads();
    if (w==1) { Quat p; p.x=w0t.x;p.y=w0t.y;p.z=w0t.z;p.w=w0t.w; inc=qmul(p,inc); }
    { float4 o; o.x=inc.x;o.y=inc.y;o.z=inc.z;o.w=inc.w; all[c]=o; }
    __syncthreads();
    float4 pre;
    if (c==0) { pre.x=0.f;pre.y=0.f;pre.z=0.f;pre.w=1.f; }
    else pre=all[c-1];
    reinterpret_cast<float4*>(scr+QPRE_SOFF)[b*NCH+c]=pre;
}

// ---------------------------------------------------------------------------
// C: main fused kernel. wave = chunk. Writes outq, vel/pos chunk partials,
//    covariance chunk composites (Phi 28 + S 45 unique floats per chunk).
// ---------------------------------------------------------------------------
#define RSTR 66
__global__ __launch_bounds__(256) void k_main(
    const float* __restrict__ dt, const float* __restrict__ gyro,
    const float* __restrict__ acc, float* __restrict__ scr,
    float* __restrict__ outq, float* __restrict__ cov)
{
    __shared__ float red[4][23][RSTR];   // 24,288 B
    const int bid=blockIdx.x, b=bid>>5, wg=bid&31;
    const int tid=threadIdx.x, lane=tid&63, wid=tid>>6;
    const int c=wg*4+wid;
    const long k=(long)b*FF+(long)c*64+lane;

    const float d=dt[k];
    const float wx=gyro[3*k+0]*d, wy=gyro[3*k+1]*d, wz=gyro[3*k+2]*d;
    Quat dq=qexp3(wx,wy,wz);

    // within-chunk inclusive quat prefix
    Quat qloc=dq;
#pragma unroll
    for (int s=1;s<64;s<<=1) {
        Quat p=qshfl_up(qloc,s);
        if (lane>=s) qloc=qmul(p,qloc);
    }
    float4 tp=reinterpret_cast<const float4*>(scr+QPRE_SOFF)[b*NCH+c];
    Quat qpre; qpre.x=tp.x; qpre.y=tp.y; qpre.z=tp.z; qpre.w=tp.w;
    Quat qi=qmul(qpre,qloc);
    { float4 o; o.x=qi.x;o.y=qi.y;o.z=qi.z;o.w=qi.w;
      reinterpret_cast<float4*>(outq)[k]=o; }

    Quat ql1=qshfl_up(qloc,1);
    Quat qp = (lane==0) ? qpre : qmul(qpre,ql1);

    // a = acc - R(qi)^T g
    float a0=acc[3*k+0]-GRAV*2.0f*(qi.x*qi.z-qi.y*qi.w);
    float a1=acc[3*k+1]-GRAV*2.0f*(qi.y*qi.z+qi.x*qi.w);
    float a2=acc[3*k+2]-GRAV*(1.0f-2.0f*(qi.x*qi.x+qi.y*qi.y));

    float Rp[9]; quat2mat(qp,Rp);
    float s0=(Rp[0]*a0+Rp[1]*a1+Rp[2]*a2)*d;
    float s1=(Rp[3]*a0+Rp[4]*a1+Rp[5]*a2)*d;
    float s2=(Rp[6]*a0+Rp[7]*a1+Rp[8]*a2)*d;

    // chunk vel/pos partials
    float td=d, l0=s0, l1=s1, l2=s2;
#pragma unroll
    for (int s=1;s<64;s<<=1) {
        float p3=__shfl_up(td,s), p0=__shfl_up(l0,s), p1=__shfl_up(l1,s), p2=__shfl_up(l2,s);
        if (lane>=s) { td+=p3; l0+=p0; l1+=p1; l2+=p2; }
    }
    float w0=(l0-s0)*d+0.5f*s0*d;
    float w1=(l1-s1)*d+0.5f*s1*d;
    float w2=(l2-s2)*d+0.5f*s2*d;
#pragma unroll
    for (int m=1;m<64;m<<=1) {
        w0+=__shfl_xor(w0,m); w1+=__shfl_xor(w1,m); w2+=__shfl_xor(w2,m);
    }
    if (lane==63) {
        float* vp=scr+VP_SOFF+(long)(b*NCH+c)*8;
        vp[0]=l0; vp[1]=l1; vp[2]=l2; vp[3]=w0; vp[4]=w1; vp[5]=w2; vp[6]=td;
    }

    // ---- covariance composite ----
    float Rd[9]; quat2mat(dq,Rd);
    float D[9];
    D[0]=Rd[0]; D[1]=Rd[3]; D[2]=Rd[6];
    D[3]=Rd[1]; D[4]=Rd[4]; D[5]=Rd[7];
    D[6]=Rd[2]; D[7]=Rd[5]; D[8]=Rd[8];

    float P[9], Q[9];
#pragma unroll
    for (int i=0;i<3;i++) {
        float r0=Rp[3*i+0], r1=Rp[3*i+1], r2=Rp[3*i+2];
        float Ra0 = a2*r1 - a1*r2;
        float Ra1 = a0*r2 - a2*r0;
        float Ra2 = a1*r0 - a0*r1;
        P[3*i+0] = -d*Ra0; P[3*i+1] = -d*Ra1; P[3*i+2] = -d*Ra2;
        Q[3*i+0] = 0.5f*d*P[3*i+0]; Q[3*i+1] = 0.5f*d*P[3*i+1]; Q[3*i+2] = 0.5f*d*P[3*i+2];
    }
    float T = d;

    float th2 = wx*wx + wy*wy + wz*wz;
    float c1, c2;
    if (th2 < 1e-8f) { c1 = 0.5f - th2*(1.0f/24.0f); c2 = (1.0f/6.0f) - th2*(1.0f/120.0f); }
    else { float th = sqrtf(th2); c1 = (1.0f-cosf(th))/th2; c2 = (th - sinf(th))/(th2*th); }
    float J[9];
    {
        float dg = 1.0f - c2*th2;
        J[0]=dg + c2*wx*wx;      J[1]= c1*wz + c2*wx*wy;  J[2]=-c1*wy + c2*wx*wz;
        J[3]=-c1*wz + c2*wx*wy;  J[4]=dg + c2*wy*wy;      J[5]= c1*wx + c2*wy*wz;
        J[6]= c1*wy + c2*wx*wz;  J[7]=-c1*wx + c2*wy*wz;  J[8]=dg + c2*wz*wz;
    }
    float G[9]; mm_nt(J, J, G);
    {
        float gs = GCOV*d*d;
#pragma unroll
        for (int i=0;i<9;i++) G[i] *= gs;
    }
    const float av = ACOV*d*d;
    const float bv = 0.5f*ACOV*d*d*d;
    const float cv = 0.25f*ACOV*d*d*d*d;

    // wave inclusive suffix scan of (D,P,Q,T)
#pragma unroll
    for (int s=1;s<64;s<<=1) {
        float pD[9], pP[9], pQ[9], pT;
#pragma unroll
        for (int i=0;i<9;i++){ pD[i]=__shfl_down(D[i],s); pP[i]=__shfl_down(P[i],s); pQ[i]=__shfl_down(Q[i],s); }
        pT = __shfl_down(T, s);
        if (lane + s < 64) {
            float nD[9], nP[9], nQ[9];
            mm_nn(pD, D, nD); mm_nn(pP, D, nP); mm_nn(pQ, D, nQ);
#pragma unroll
            for (int i=0;i<9;i++){
                float np = nP[i] + P[i];
                float nq = nQ[i] + pT*P[i] + Q[i];
                D[i]=nD[i]; P[i]=np; Q[i]=nq;
            }
            T += pT;
        }
    }
    const long wsbase = ((long)b*NCH + c)*SLOT;
    if (lane==0) {
#pragma unroll
        for (int i=0;i<9;i++){ cov[wsbase+i]=D[i]; cov[wsbase+9+i]=P[i]; cov[wsbase+18+i]=Q[i]; }
        cov[wsbase+27] = T;
    }
    // exclusive suffix shift
    {
        float pD[9], pP[9], pQ[9], pT;
#pragma unroll
        for (int i=0;i<9;i++){ pD[i]=__shfl_down(D[i],1); pP[i]=__shfl_down(P[i],1); pQ[i]=__shfl_down(Q[i],1); }
        pT = __shfl_down(T, 1);
        if (lane==63) {
#pragma unroll
            for (int i=0;i<9;i++){ D[i]=(i%4==0)?1.f:0.f; P[i]=0.f; Q[i]=0.f; }
            T = 0.f;
        } else {
#pragma unroll
            for (int i=0;i<9;i++){ D[i]=pD[i]; P[i]=pP[i]; Q[i]=pQ[i]; }
            T = pT;
        }
    }
    // term = Psi N Psi^T, 45 unique elements:
    //  0-8 Arv | 9-17 Arp | 18-26 Avp | 27-32 Arr(tri) | 33-38 Avv(tri) | 39-44 App(tri)
    float S45[45];
    {
        float M1[9];
        mm_nn(D, G, M1);
        mm_nt_sym(M1, D, S45+27);       // Arr
        mm_nt(M1, P, S45+0);            // Arv
        mm_nt(M1, Q, S45+9);            // Arp
        mm_nn(P, G, M1);
        mm_nt_sym(M1, P, S45+33);       // Avv
        mm_nt(M1, Q, S45+18);           // Avp
        mm_nn(Q, G, M1);
        mm_nt_sym(M1, Q, S45+39);       // App
        S45[33]+=av; S45[36]+=av; S45[38]+=av;
        float vpd = av*T + bv;
        S45[18]+=vpd; S45[22]+=vpd; S45[26]+=vpd;
        float ppd = av*T*T + 2.0f*bv*T + cv;
        S45[39]+=ppd; S45[42]+=ppd; S45[44]+=ppd;
    }

    // per-wave LDS transpose reduction over lanes, two rounds (23 + 22 elems)
#pragma unroll
    for (int e=0;e<23;e++) red[wid][e][lane] = S45[e];
    __syncthreads();
    float r1 = 0.f;
    if (lane < 23) {
        const float* row = &red[wid][lane][0];
        float ax=0.f, ay=0.f;
#pragma unroll
        for (int i=0;i<32;i++) {
            float2 v = reinterpret_cast<const float2*>(row)[i];
            ax += v.x; ay += v.y;
        }
        r1 = ax + ay;
    }
    __syncthreads();
#pragma unroll
    for (int e=0;e<22;e++) red[wid][e][lane] = S45[23+e];
    __syncthreads();
    float r2 = 0.f;
    if (lane < 22) {
        const float* row = &red[wid][lane][0];
        float ax=0.f, ay=0.f;
#pragma unroll
        for (int i=0;i<32;i++) {
            float2 v = reinterpret_cast<const float2*>(row)[i];
            ax += v.x; ay += v.y;
        }
        r2 = ax + ay;
    }
    if (lane < 23) cov[wsbase+28+lane] = r1;
    if (lane < 22) cov[wsbase+28+23+lane] = r2;
}

// ---------------------------------------------------------------------------
// D: per-batch scans of vel/pos chunk partials -> exclusive (V, Pp) per chunk.
// ---------------------------------------------------------------------------
__global__ __launch_bounds__(128) void k_vpscan(
    const float* __restrict__ scr, float* __restrict__ vpre)
{
    const int b=blockIdx.x, c=threadIdx.x, lane=c&63, w=c>>6;
    __shared__ float w0t[3];
    __shared__ float all3[NCH][3];
    const float* vp=scr+VP_SOFF+(long)(b*NCH+c)*8;
    float Lv0=vp[0],Lv1=vp[1],Lv2=vp[2],Sw0=vp[3],Sw1=vp[4],Sw2=vp[5],Td=vp[6];

    float i0=Lv0,i1=Lv1,i2=Lv2;
#pragma unroll
    for (int s=1;s<64;s<<=1) {
        float p0=__shfl_up(i0,s),p1=__shfl_up(i1,s),p2=__shfl_up(i2,s);
        if (lane>=s){ i0+=p0; i1+=p1; i2+=p2; }
    }
    if (w==0 && lane==63){ w0t[0]=i0; w0t[1]=i1; w0t[2]=i2; }
    __syncthreads();
    if (w==1){ i0+=w0t[0]; i1+=w0t[1]; i2+=w0t[2]; }
    all3[c][0]=i0; all3[c][1]=i1; all3[c][2]=i2;
    __syncthreads();
    float V0=(c==0)?0.f:all3[c-1][0];
    float V1=(c==0)?0.f:all3[c-1][1];
    float V2=(c==0)?0.f:all3[c-1][2];
    __syncthreads();

    float u0=V0*Td+Sw0, u1=V1*Td+Sw1, u2=V2*Td+Sw2;
    i0=u0; i1=u1; i2=u2;
#pragma unroll
    for (int s=1;s<64;s<<=1) {
        float p0=__shfl_up(i0,s),p1=__shfl_up(i1,s),p2=__shfl_up(i2,s);
        if (lane>=s){ i0+=p0; i1+=p1; i2+=p2; }
    }
    if (w==0 && lane==63){ w0t[0]=i0; w0t[1]=i1; w0t[2]=i2; }
    __syncthreads();
    if (w==1){ i0+=w0t[0]; i1+=w0t[1]; i2+=w0t[2]; }
    all3[c][0]=i0; all3[c][1]=i1; all3[c][2]=i2;
    __syncthreads();
    float P0=(c==0)?0.f:all3[c-1][0];
    float P1=(c==0)?0.f:all3[c-1][1];
    float P2=(c==0)?0.f:all3[c-1][2];

    float* o=vpre+(long)(b*NCH+c)*8;
    o[0]=V0; o[1]=V1; o[2]=V2; o[3]=P0; o[4]=P1; o[5]=P2;
}

// ---------------------------------------------------------------------------
// E: final vel/pos emit. wave = chunk.
// ---------------------------------------------------------------------------
__global__ __launch_bounds__(256) void k_emit(
    const float* __restrict__ dt, const float* __restrict__ acc,
    const float* __restrict__ q, const float* __restrict__ pos0,
    const float* __restrict__ vel0, const float* __restrict__ vpre,
    float* __restrict__ outv, float* __restrict__ outp)
{
    const int bid=blockIdx.x, b=bid>>5, wg=bid&31;
    const int tid=threadIdx.x, lane=tid&63, wid=tid>>6;
    const int c=wg*4+wid;
    const long k=(long)b*FF+(long)c*64+lane;

    const float d=dt[k];
    float4 tq=reinterpret_cast<const float4*>(q)[k];
    Quat qi; qi.x=tq.x; qi.y=tq.y; qi.z=tq.z; qi.w=tq.w;

    float a0=acc[3*k+0]-GRAV*2.0f*(qi.x*qi.z-qi.y*qi.w);
    float a1=acc[3*k+1]-GRAV*2.0f*(qi.y*qi.z+qi.x*qi.w);
    float a2=acc[3*k+2]-GRAV*(1.0f-2.0f*(qi.x*qi.x+qi.y*qi.y));

    Quat qp=qshfl_up(qi,1);
    if (lane==0) {
        if (c==0) { qp.x=0.f; qp.y=0.f; qp.z=0.f; qp.w=1.f; }
        else { float4 t2=reinterpret_cast<const float4*>(q)[k-1];
               qp.x=t2.x; qp.y=t2.y; qp.z=t2.z; qp.w=t2.w; }
    }
    float Rp[9]; quat2mat(qp,Rp);
    float s0=(Rp[0]*a0+Rp[1]*a1+Rp[2]*a2)*d;
    float s1=(Rp[3]*a0+Rp[4]*a1+Rp[5]*a2)*d;
    float s2=(Rp[6]*a0+Rp[7]*a1+Rp[8]*a2)*d;

    float td=d, l0=s0, l1=s1, l2=s2;
#pragma unroll
    for (int s=1;s<64;s<<=1) {
        float p3=__shfl_up(td,s), p0=__shfl_up(l0,s), p1=__shfl_up(l1,s), p2=__shfl_up(l2,s);
        if (lane>=s) { td+=p3; l0+=p0; l1+=p1; l2+=p2; }
    }
    float w0=(l0-s0)*d+0.5f*s0*d;
    float w1=(l1-s1)*d+0.5f*s1*d;
    float w2=(l2-s2)*d+0.5f*s2*d;
    float sw0=w0, sw1=w1, sw2=w2;
#pragma unroll
    for (int s=1;s<64;s<<=1) {
        float p0=__shfl_up(sw0,s),p1=__shfl_up(sw1,s),p2=__shfl_up(sw2,s);
        if (lane>=s){ sw0+=p0; sw1+=p1; sw2+=p2; }
    }

    const float* vr=vpre+(long)(b*NCH+c)*8;
    float V0=vr[0],V1=vr[1],V2=vr[2],P0=vr[3],P1=vr[4],P2=vr[5];
    float v0x=vel0[3*b+0], v0y=vel0[3*b+1], v0z=vel0[3*b+2];
    float p0x=pos0[3*b+0], p0y=pos0[3*b+1], p0z=pos0[3*b+2];

    outv[3*k+0]=v0x+V0+l0;
    outv[3*k+1]=v0y+V1+l1;
    outv[3*k+2]=v0z+V2+l2;
    outp[3*k+0]=p0x+P0+V0*td+sw0;
    outp[3*k+1]=p0y+P1+V1*td+sw1;
    outp[3*k+2]=p0z+P2+V2*td+sw2;
}

// ---------------------------------------------------------------------------
// K4: combine 128 compact chunk composites per batch -> final 9x9 covariance.
// Phi: slot[0..27] = D,P,Q,T. S (45): Arv0 Arp9 Avp18 Arr27t Avv33t App39t.
// ---------------------------------------------------------------------------
__device__ __forceinline__ void congr45(const float* Phi, const float* S, float* O)
{
    const float* D=Phi; const float* P=Phi+9; const float* Q=Phi+18; const float T=Phi[27];
    const float* Arv=S+0; const float* Arp=S+9; const float* Avp=S+18;
    float Arr[9], Avv[9], App[9];
    expand_sym(S+27,Arr); expand_sym(S+33,Avv); expand_sym(S+39,App);

    float M1[9], M2[9], M3[9], t1[9], t6[6];
    mm_nn(D,Arr,M1); mm_nn(D,Arv,M2); mm_nn(D,Arp,M3);
    mm_nt_sym(M1, D, O+27);                          // O_rr (tri)
    mm_nt(M1, P, t1);
#pragma unroll
    for (int i=0;i<9;i++) O[0+i] = t1[i] + M2[i];    // O_rv
    mm_nt(M1, Q, t1);
#pragma unroll
    for (int i=0;i<9;i++) O[9+i] = t1[i] + T*M2[i] + M3[i];  // O_rp

    float W1[9], W2[9], W3[9];
    mm_nn(P, Arr, W1);
#pragma unroll
    for (int i=0;i<3;i++)
#pragma unroll
    for (int j=0;j<3;j++) W1[3*i+j] += Arv[3*j+i];
    mm_nn(P, Arv, W2);
#pragma unroll
    for (int i=0;i<9;i++) W2[i] += Avv[i];
    mm_nn(P, Arp, W3);
#pragma unroll
    for (int i=0;i<9;i++) W3[i] += Avp[i];
    mm_nt_sym(W1, P, t6);                            // O_vv (tri)
    O[33+0]=t6[0]+W2[0]; O[33+1]=t6[1]+W2[1]; O[33+2]=t6[2]+W2[2];
    O[33+3]=t6[3]+W2[4]; O[33+4]=t6[4]+W2[5]; O[33+5]=t6[5]+W2[8];
    mm_nt(W1, Q, t1);
#pragma unroll
    for (int i=0;i<9;i++) O[18+i] = t1[i] + T*W2[i] + W3[i];  // O_vp

    float U1[9], U2[9], U3[9];
    mm_nn(Q, Arr, U1);
#pragma unroll
    for (int i=0;i<3;i++)
#pragma unroll
    for (int j=0;j<3;j++) U1[3*i+j] += T*Arv[3*j+i] + Arp[3*j+i];
    mm_nn(Q, Arv, U2);
#pragma unroll
    for (int i=0;i<3;i++)
#pragma unroll
    for (int j=0;j<3;j++) U2[3*i+j] += T*Avv[3*i+j] + Avp[3*j+i];
    mm_nn(Q, Arp, U3);
#pragma unroll
    for (int i=0;i<9;i++) U3[i] += T*Avp[i] + App[i];
    mm_nt_sym(U1, Q, t6);                            // O_pp (tri)
    O[39+0]=t6[0]+T*U2[0]+U3[0]; O[39+1]=t6[1]+T*U2[1]+U3[1]; O[39+2]=t6[2]+T*U2[2]+U3[2];
    O[39+3]=t6[3]+T*U2[4]+U3[4]; O[39+4]=t6[4]+T*U2[5]+U3[5]; O[39+5]=t6[5]+T*U2[8]+U3[8];
}

__global__ __launch_bounds__(128) void k_covcomb(
    const float* __restrict__ cov, float* __restrict__ outc)
{
    __shared__ float cp[NCH*SLOT];   // 37,376 B
    const int b = blockIdx.x;
    const int c = threadIdx.x;
    // straight contiguous copy (coalesced, pipeline-friendly)
    for (int idx=c; idx<NCH*SLOT; idx+=128) cp[idx] = cov[(long)b*NCH*SLOT + idx];
    __syncthreads();

    // inclusive suffix scan of the Phi parts (first 28 floats of each slot)
    for (int s=1;s<NCH;s<<=1) {
        float aD[9],aP[9],aQ[9],aT=0.f;
        float bD[9],bP[9],bQ[9],bT;
        bool act = (c+s) < NCH;
#pragma unroll
        for (int i=0;i<9;i++){ bD[i]=cp[c*SLOT+i]; bP[i]=cp[c*SLOT+9+i]; bQ[i]=cp[c*SLOT+18+i]; }
        bT = cp[c*SLOT+27];
        if (act) {
#pragma unroll
            for (int i=0;i<9;i++){ aD[i]=cp[(c+s)*SLOT+i]; aP[i]=cp[(c+s)*SLOT+9+i]; aQ[i]=cp[(c+s)*SLOT+18+i]; }
            aT = cp[(c+s)*SLOT+27];
        }
        __syncthreads();
        if (act) {
            float nD[9], nP[9], nQ[9];
            mm_nn(aD, bD, nD); mm_nn(aP, bD, nP); mm_nn(aQ, bD, nQ);
#pragma unroll
            for (int i=0;i<9;i++){
                cp[c*SLOT+i]    = nD[i];
                cp[c*SLOT+9+i]  = nP[i] + bP[i];
                cp[c*SLOT+18+i] = nQ[i] + aT*bP[i] + bQ[i];
            }
            cp[c*SLOT+27] = aT + bT;
        }
        __syncthreads();
    }

    // exclusive suffix Phi for this chunk
    float Phi[28];
    if (c < NCH-1) {
#pragma unroll
        for (int i=0;i<28;i++) Phi[i]=cp[(c+1)*SLOT+i];
    } else {
#pragma unroll
        for (int i=0;i<9;i++){ Phi[i]=(i%4==0)?1.f:0.f; Phi[9+i]=0.f; Phi[18+i]=0.f; }
        Phi[27]=0.f;
    }
    float S[45], O[45];
#pragma unroll
    for (int i=0;i<45;i++) S[i] = cp[c*SLOT+28+i];
    congr45(Phi, S, O);
#pragma unroll
    for (int i=0;i<45;i++) cp[c*SLOT+28+i] = O[i];
    __syncthreads();

    // tree sum of the 45-float terms
    for (int s=64;s>0;s>>=1) {
        if (c < s) {
#pragma unroll
            for (int i=0;i<45;i++) cp[c*SLOT+28+i] += cp[(c+s)*SLOT+28+i];
        }
        __syncthreads();
    }

    if (c < 81) {
        int i = c/9, j = c%9;
        int bi = i/3, ii = i%3, bj = j/3, jj = j%3;
        int lo = (ii<jj)?ii:jj, hi = (ii<jj)?jj:ii;
        int tix = (lo==0)?hi:((lo==1)?(2+hi):5);
        const float* S0 = &cp[28];
        float v;
        if      (bi==0 && bj==0) v = S0[27 + tix];        // Arr
        else if (bi==0 && bj==1) v = S0[0  + 3*ii + jj];  // Arv
        else if (bi==0 && bj==2) v = S0[9  + 3*ii + jj];  // Arp
        else if (bi==1 && bj==0) v = S0[0  + 3*jj + ii];  // Arv^T
        else if (bi==1 && bj==1) v = S0[33 + tix];        // Avv
        else if (bi==1 && bj==2) v = S0[18 + 3*ii + jj];  // Avp
        else if (bi==2 && bj==0) v = S0[9  + 3*jj + ii];  // Arp^T
        else if (bi==2 && bj==1) v = S0[18 + 3*jj + ii];  // Avp^T
        else                     v = S0[39 + tix];        // App
        outc[(long)b*81 + c] = v;
    }
}

// ---------------------------------------------------------------------------
extern "C" void kernel_launch(void* const* d_in, const int* in_sizes, int n_in,
                              void* d_out, int out_size, void* d_ws, size_t ws_size,
                              hipStream_t stream)
{
    const float* dt   = (const float*)d_in[0];
    const float* gyro = (const float*)d_in[1];
    const float* acc  = (const float*)d_in[2];
    const float* pos0 = (const float*)d_in[3];
    const float* vel0 = (const float*)d_in[4];

    float* out  = (float*)d_out;
    float* outq = out;
    float* outv = out  + (long)BB*FF*4;
    float* outp = outv + (long)BB*FF*3;
    float* outc = outp + (long)BB*FF*3;

    float* ws   = (float*)d_ws;           // 1,327,104 bytes used
    float* cov  = ws + COV_OFF;
    float* vpre = ws + VPRE_OFF;
    float* scr  = outv;                   // staging scratch, consumed before E

    hipLaunchKernelGGL(k_chunktot, dim3(BB*32), dim3(256), 0, stream, dt, gyro, scr);
    hipLaunchKernelGGL(k_qpre,     dim3(BB),    dim3(128), 0, stream, scr);
    hipLaunchKernelGGL(k_main,     dim3(BB*32), dim3(256), 0, stream, dt, gyro, acc, scr, outq, cov);
    hipLaunchKernelGGL(k_vpscan,   dim3(BB),    dim3(128), 0, stream, scr, vpre);
    hipLaunchKernelGGL(k_emit,     dim3(BB*32), dim3(256), 0, stream, dt, acc, outq, pos0, vel0, vpre, outv, outp);
    hipLaunchKernelGGL(k_covcomb,  dim3(BB),    dim3(128), 0, stream, cov, outc);
}